// Round 3
// baseline (317.233 us; speedup 1.0000x reference)
//
#include <hip/hip_runtime.h>

#define POOL 7
#define NROIS 1000
#define NCELLS (NROIS * POOL * POOL)       // 49000 output cells
#define IMG_W 128
#define NCH 1024
#define NXCD 8
#define ROIS_PER_XCD (NROIS / NXCD)        // 125
#define CELLS_PER_XCD (ROIS_PER_XCD * 49)  // 6125
#define BLKS_PER_XCD 256
#define CHUNK 24                           // ceil(6125/256): cells per block

typedef float f4 __attribute__((ext_vector_type(4)));

// Issue phase of the 2-deep pipeline: compute coords (scalar path — cell is
// block-uniform) and ISSUE the 4 corner-row loads. Results are not used by
// the caller until the next loop iteration, so the compiler keeps these
// loads in flight (8 outstanding per thread in steady state).
__device__ __forceinline__ void issue_cell(
    const float* __restrict__ img, const int* __restrict__ rois,
    float* __restrict__ out, unsigned cell, unsigned choff,
    f4& a, f4& b, f4& c, f4& d, float& wx, float& wy, f4*& po)
{
    const unsigned roi = cell / 49u;
    const unsigned c49 = cell - roi * 49u;
    const unsigned py  = c49 / 7u;
    const unsigned px  = c49 - py * 7u;

    const int4 r = ((const int4*)rois)[roi];   // block-uniform -> s_load
    const int x = r.x, y = r.y, w = r.z, h = r.w;

    // y-axis source coords (match reference op order exactly)
    const float hf = (float)h;
    float fy = ((float)py + 0.5f) * (hf / (float)POOL) - 0.5f;
    fy = fminf(fmaxf(fy, 0.0f), fmaxf(hf - 1.0f, 0.0f));
    const int   iy0 = (int)floorf(fy);
    const int   iy1 = min(iy0 + 1, h - 1);
    wy = fy - (float)iy0;
    const int   y0  = y + iy0;
    const int   y1  = y + iy1;

    // x-axis source coords
    const float wf = (float)w;
    float fx = ((float)px + 0.5f) * (wf / (float)POOL) - 0.5f;
    fx = fminf(fmaxf(fx, 0.0f), fmaxf(wf - 1.0f, 0.0f));
    const int   ix0 = (int)floorf(fx);
    const int   ix1 = min(ix0 + 1, w - 1);
    wx = fx - (float)ix0;
    const int   x0  = x + ix0;
    const int   x1  = x + ix1;

    const f4* p00 = (const f4*)(img + ((size_t)y0 * IMG_W + x0) * NCH + choff);
    const f4* p01 = (const f4*)(img + ((size_t)y0 * IMG_W + x1) * NCH + choff);
    const f4* p10 = (const f4*)(img + ((size_t)y1 * IMG_W + x0) * NCH + choff);
    const f4* p11 = (const f4*)(img + ((size_t)y1 * IMG_W + x1) * NCH + choff);

    a = *p00;                                  // issue loads; no use yet
    b = *p01;
    c = *p10;
    d = *p11;
    po = (f4*)(out + (size_t)cell * NCH + choff);
}

// Grid-stride ROI bilinear pooling with 2-deep software pipeline.
// 2048 long-lived blocks (8/CU); each walks CHUNK consecutive cells of its
// XCD's contiguous ROI range. Consecutive cells share corner rows -> L1
// read reuse. Loads for cell i+1 are issued before cell i's compute, so
// each thread holds 8 loads in flight and waves never single-shot stall.
__global__ __launch_bounds__(256) void roi_pool_kernel(
    const float* __restrict__ img,
    const int* __restrict__ rois,
    float* __restrict__ out)
{
    const unsigned bid  = blockIdx.x;
    const unsigned xcd  = bid & 7u;            // presumed XCD (round-robin)
    const unsigned blk  = bid >> 3;            // 0..255 within XCD

    const unsigned xbase = xcd * CELLS_PER_XCD;
    unsigned cc  = xbase + blk * CHUNK;
    const unsigned end = min(cc + CHUNK, xbase + CELLS_PER_XCD);
    if (cc >= end) return;

    const unsigned choff = threadIdx.x * 4u;   // 256 thr x f4 = full 1024-ch row

    f4 a, b, c, d; float wx, wy; f4* po;
    issue_cell(img, rois, out, cc, choff, a, b, c, d, wx, wy, po);

    while (true) {
        const unsigned cn = cc + 1;
        const bool more = (cn < end);

        f4 a2, b2, c2, d2; float wx2, wy2; f4* po2;
        if (more)
            issue_cell(img, rois, out, cn, choff, a2, b2, c2, d2, wx2, wy2, po2);

        // compute current cell (compiler inserts vmcnt wait for a..d here,
        // leaving the next cell's 4 loads outstanding)
        const float owx = 1.0f - wx;
        const float owy = 1.0f - wy;
        const f4 top = a * owx + b * wx;
        const f4 bot = c * owx + d * wx;
        const f4 res = top * owy + bot * wy;
        __builtin_nontemporal_store(res, po);

        if (!more) break;
        a = a2; b = b2; c = c2; d = d2;
        wx = wx2; wy = wy2; po = po2;
        cc = cn;
    }
}

extern "C" void kernel_launch(void* const* d_in, const int* in_sizes, int n_in,
                              void* d_out, int out_size, void* d_ws, size_t ws_size,
                              hipStream_t stream)
{
    const float* img  = (const float*)d_in[0];
    const int*   rois = (const int*)d_in[1];
    float*       out  = (float*)d_out;

    const int nblocks = BLKS_PER_XCD * NXCD;   // 2048 blocks, 8 per CU
    roi_pool_kernel<<<nblocks, 256, 0, stream>>>(img, rois, out);
}

// Round 4
// 276.983 us; speedup vs baseline: 1.1453x; 1.1453x over previous
//
#include <hip/hip_runtime.h>

#define POOL 7
#define NROIS 1000
#define NCELLS (NROIS * POOL * POOL)     // 49000 output cells
#define IMG_W 128
#define NCH 1024
#define NXCD 8
#define CG_CH 128                        // channels per XCD slice (512 B)
#define CELLS_PER_BLK 8                  // 256 thr = 8 cells x 32 lanes x f4
#define NBLK_PER_XCD (NCELLS / CELLS_PER_BLK)   // 6125

typedef float f4 __attribute__((ext_vector_type(4)));

// Channel-sharded ROI bilinear pooling, G=8 (one 128-ch slice per XCD).
// bid%8 == XCD id (round-robin dispatch heuristic). XCD k processes the
// 512 B channel slice [k*128, (k+1)*128) of ALL 49000 cells. Its image
// working set is an exclusive 8 MB channel slice (~6.5 MB touched), mostly
// L2-resident; every image byte is fetched from HBM by exactly one XCD ->
// ideal chip-wide FETCH = 64 MB (vs 336 MB for unsharded). Reads and
// writes move in 512 B segments (vs 128 B in the G=32 variant).
__global__ __launch_bounds__(256) void roi_pool_kernel(
    const float* __restrict__ img,
    const int* __restrict__ rois,
    float* __restrict__ out)
{
    const unsigned bid  = blockIdx.x;
    const unsigned xcd  = bid & 7u;            // presumed XCD of this block
    const unsigned cblk = bid >> 3;            // 0..6124 cell-block in XCD
    const unsigned t    = threadIdx.x;         // 0..255
    const unsigned cell = cblk * CELLS_PER_BLK + (t >> 5);  // 32 lanes/cell
    const unsigned lane = t & 31u;

    const unsigned roi = cell / 49u;
    const unsigned c49 = cell - roi * 49u;
    const unsigned py  = c49 / 7u;
    const unsigned px  = c49 - py * 7u;

    const int4 r = ((const int4*)rois)[roi];   // x, y, w, h
    const int x = r.x, y = r.y, w = r.z, h = r.w;

    // y-axis source coords (match reference op order exactly)
    const float hf = (float)h;
    float fy = ((float)py + 0.5f) * (hf / (float)POOL) - 0.5f;
    fy = fminf(fmaxf(fy, 0.0f), fmaxf(hf - 1.0f, 0.0f));
    const int   iy0 = (int)floorf(fy);
    const int   iy1 = min(iy0 + 1, h - 1);
    const float wy  = fy - (float)iy0;
    const int   y0  = y + iy0;
    const int   y1  = y + iy1;

    // x-axis source coords
    const float wf = (float)w;
    float fx = ((float)px + 0.5f) * (wf / (float)POOL) - 0.5f;
    fx = fminf(fmaxf(fx, 0.0f), fmaxf(wf - 1.0f, 0.0f));
    const int   ix0 = (int)floorf(fx);
    const int   ix1 = min(ix0 + 1, w - 1);
    const float wx  = fx - (float)ix0;
    const int   x0  = x + ix0;
    const int   x1  = x + ix1;

    // channel offset: this XCD's slice base + lane quad
    const unsigned choff = xcd * CG_CH + lane * 4u;

    const f4* p00 = (const f4*)(img + ((size_t)y0 * IMG_W + x0) * NCH + choff);
    const f4* p01 = (const f4*)(img + ((size_t)y0 * IMG_W + x1) * NCH + choff);
    const f4* p10 = (const f4*)(img + ((size_t)y1 * IMG_W + x0) * NCH + choff);
    const f4* p11 = (const f4*)(img + ((size_t)y1 * IMG_W + x1) * NCH + choff);
    f4* po = (f4*)(out + (size_t)cell * NCH + choff);

    const f4 a = *p00;
    const f4 b = *p01;
    const f4 c = *p10;
    const f4 d = *p11;

    const float owx = 1.0f - wx;
    const float owy = 1.0f - wy;

    const f4 top = a * owx + b * wx;
    const f4 bot = c * owx + d * wx;
    const f4 res = top * owy + bot * wy;

    __builtin_nontemporal_store(res, po);
}

extern "C" void kernel_launch(void* const* d_in, const int* in_sizes, int n_in,
                              void* d_out, int out_size, void* d_ws, size_t ws_size,
                              hipStream_t stream)
{
    const float* img  = (const float*)d_in[0];
    const int*   rois = (const int*)d_in[1];
    float*       out  = (float*)d_out;

    const int nblocks = NBLK_PER_XCD * NXCD;   // 49000
    roi_pool_kernel<<<nblocks, 256, 0, stream>>>(img, rois, out);
}